// Round 11
// baseline (252.966 us; speedup 1.0000x reference)
//
#include <hip/hip_runtime.h>

// ---------- types / helpers ----------
typedef __bf16 bf16x8 __attribute__((ext_vector_type(8)));
typedef float  f32x4  __attribute__((ext_vector_type(4)));
typedef unsigned short u16x8 __attribute__((ext_vector_type(8)));

__device__ __forceinline__ float b2f(unsigned short u) {
  union { float f; unsigned int i; } v; v.i = ((unsigned int)u) << 16; return v.f;
}
__device__ __forceinline__ unsigned short f2b(float f) {
  union { float f; unsigned int i; } v; v.f = f;
  unsigned int r = v.i + 0x7fffu + ((v.i >> 16) & 1u);   // RNE
  return (unsigned short)(r >> 16);
}

__device__ __forceinline__ void async_copy16(const unsigned short* g, unsigned short* l) {
  __builtin_amdgcn_global_load_lds(
      (__attribute__((address_space(1))) void*)g,
      (__attribute__((address_space(3))) void*)l, 16, 0, 0);   // offset MUST be 0 (R8 pitfall)
}

// ---------- prep: z<7 weight transpose f32[K][N]->bf16[N][K]; z==7 conv-w; z>=8 cast x ----------
__global__ void k_prep(const float* w0, const float* w1_, const float* w2_,
                       const float* w3_, const float* w4_, const float* w5_,
                       const float* w6_, unsigned short* dst,
                       const float* cw, float* cwT,
                       const float* x, unsigned short* xb) {
  const int tx = threadIdx.x, ty = threadIdx.y;   // 32 x 8
  const int z = blockIdx.z;
  if (z >= 8) {   // cast x [8,1022,1024] f32 -> [8,1024,1024] bf16 (rows 1022/1023 zero)
    const int fb = (z - 8) * 1024 + blockIdx.y * 32 + blockIdx.x;
    const size_t i = ((size_t)(fb * 256 + ty * 32 + tx)) << 2;
    const int d = (int)(i & 1023);
    const int row = (int)(i >> 10);
    const int t = row & 1023, b = row >> 10;
    float4 v = make_float4(0.f, 0.f, 0.f, 0.f);
    if (t < 1022) v = *(const float4*)&x[((size_t)(b * 1022 + t) << 10) + d];
    ushort4 o;
    o.x = f2b(v.x); o.y = f2b(v.y); o.z = f2b(v.z); o.w = f2b(v.w);
    *(ushort4*)&xb[i] = o;
    return;
  }
  if (z == 7) {   // conv weight transpose: cwT[j*1024+d] = cw[d*3+j]
    const int flat = (blockIdx.y * 32 + blockIdx.x) * 256 + ty * 32 + tx;
    if (flat < 3072) {
      const int d = flat & 1023, j = flat >> 10;
      cwT[flat] = cw[d * 3 + j];
    }
    return;
  }
  const float* srcs[7] = {w0, w1_, w2_, w3_, w4_, w5_, w6_};
  const float* src = srcs[z];
  unsigned short* d = dst + ((size_t)z << 20);
  __shared__ float tile[32][33];
  const int bn = blockIdx.x << 5, bk = blockIdx.y << 5;
#pragma unroll
  for (int i = 0; i < 4; ++i)
    tile[ty + i * 8][tx] = src[(size_t)(bk + ty + i * 8) * 1024 + bn + tx];
  __syncthreads();
#pragma unroll
  for (int i = 0; i < 4; ++i)
    d[(size_t)(bn + ty + i * 8) * 1024 + bk + tx] = f2b(tile[tx][ty + i * 8]);
}

// ---------- depthwise conv (k=3) + silu, 2 rows/thread, vectorized x8 ----------
__global__ void k_conv_silu(const unsigned short* __restrict__ x1, const float* __restrict__ cwT,
                            const float* __restrict__ cb, unsigned short* __restrict__ xs) {
  const int gid = blockIdx.x * 256 + threadIdx.x;   // 4096 row-pairs * 128 thr
  const int pair = gid >> 7;
  const int d0 = (gid & 127) << 3;
  const int b = pair >> 9, t0 = (pair & 511) << 1;   // rows t0, t0+1
  float w[3][8];
#pragma unroll
  for (int j = 0; j < 3; ++j) {
    float4 a = *(const float4*)&cwT[j * 1024 + d0];
    float4 c = *(const float4*)&cwT[j * 1024 + d0 + 4];
    w[j][0] = a.x; w[j][1] = a.y; w[j][2] = a.z; w[j][3] = a.w;
    w[j][4] = c.x; w[j][5] = c.y; w[j][6] = c.z; w[j][7] = c.w;
  }
  float base[8];
  {
    float4 c0 = *(const float4*)&cb[d0], c1 = *(const float4*)&cb[d0 + 4];
    base[0] = c0.x; base[1] = c0.y; base[2] = c0.z; base[3] = c0.w;
    base[4] = c1.x; base[5] = c1.y; base[6] = c1.z; base[7] = c1.w;
  }
  float rv[4][8];
#pragma unroll
  for (int r = 0; r < 4; ++r) {
    const int t = t0 + r - 2;
    if (t >= 0) {
      u16x8 v = *(const u16x8*)&x1[((size_t)(b * 1024 + t) << 10) + d0];
#pragma unroll
      for (int k = 0; k < 8; ++k) rv[r][k] = b2f(v[k]);
    } else {
#pragma unroll
      for (int k = 0; k < 8; ++k) rv[r][k] = 0.f;
    }
  }
  u16x8 o0, o1;
#pragma unroll
  for (int k = 0; k < 8; ++k) {
    float a0 = base[k] + rv[0][k] * w[0][k] + rv[1][k] * w[1][k] + rv[2][k] * w[2][k];
    float a1 = base[k] + rv[1][k] * w[0][k] + rv[2][k] * w[1][k] + rv[3][k] * w[2][k];
    o0[k] = f2b(a0 / (1.f + __expf(-a0)));
    o1[k] = f2b(a1 / (1.f + __expf(-a1)));
  }
  *(u16x8*)&xs[((size_t)(b * 1024 + t0) << 10) + d0] = o0;
  *(u16x8*)&xs[((size_t)(b * 1024 + t0 + 1) << 10) + d0] = o1;
}

// ---------- chunked scan, 2 d-lanes/thread (y=softplus*A bf16; a=exp(-y)) ----------
__global__ void k_scan1(const unsigned short* __restrict__ y, const unsigned short* __restrict__ Bx,
                        float* __restrict__ cA, float* __restrict__ cB) {
  const int p = blockIdx.x * 256 + threadIdx.x;   // 65536
  const int d2 = p & 511, bc = p >> 9;
  const int b = bc >> 4, c = bc & 15;
  const int d0 = d2 << 1;
  size_t base = ((size_t)(b * 1024 + c * 64) << 10) + d0;
  float aA0 = 1.f, aB0 = 0.f, aA1 = 1.f, aB1 = 0.f;
  for (int t = 0; t < 64; ++t) {
    const unsigned int yy = *(const unsigned int*)&y[base];
    const unsigned int bb = *(const unsigned int*)&Bx[base];
    const float a0 = __expf(-b2f((unsigned short)yy));
    const float a1 = __expf(-b2f((unsigned short)(yy >> 16)));
    aA0 *= a0; aB0 = a0 * aB0 + b2f((unsigned short)bb);
    aA1 *= a1; aB1 = a1 * aB1 + b2f((unsigned short)(bb >> 16));
    base += 1024;
  }
  const int gi = (bc << 10) + d0;
  *(float2*)&cA[gi] = make_float2(aA0, aA1);
  *(float2*)&cB[gi] = make_float2(aB0, aB1);
}
// scan2 merged in: each block recomputes its <=15-step prefix from L2-hot cA/cB
__global__ void k_scan23(const unsigned short* __restrict__ y, const unsigned short* __restrict__ Bx,
                         const float* __restrict__ cA, const float* __restrict__ cB,
                         unsigned short* __restrict__ hb) {
  const int p = blockIdx.x * 256 + threadIdx.x;
  const int d2 = p & 511, bc = p >> 9;          // bc uniform per block
  const int b = bc >> 4, c = bc & 15;
  const int d0 = d2 << 1;
  float h0 = 0.f, h1 = 0.f;
  for (int cp = 0; cp < c; ++cp) {              // c uniform per block -> no divergence
    const int gi = (((b << 4) + cp) << 10) + d0;
    const float2 a = *(const float2*)&cA[gi];
    const float2 bb = *(const float2*)&cB[gi];
    h0 = a.x * h0 + bb.x;
    h1 = a.y * h1 + bb.y;
  }
  size_t base = ((size_t)(b * 1024 + c * 64) << 10) + d0;
  for (int t = 0; t < 64; ++t) {
    const unsigned int yy = *(const unsigned int*)&y[base];
    const unsigned int bb = *(const unsigned int*)&Bx[base];
    const float a0 = __expf(-b2f((unsigned short)yy));
    const float a1 = __expf(-b2f((unsigned short)(yy >> 16)));
    h0 = a0 * h0 + b2f((unsigned short)bb);
    h1 = a1 * h1 + b2f((unsigned short)(bb >> 16));
    *(unsigned int*)&hb[base] = (unsigned int)f2b(h0) | ((unsigned int)f2b(h1) << 16);
    base += 1024;
  }
}

// ---------- GEMM: C[8192 x 1024] = A[8192x1024](bf16) * Bt[1024 x 1024]^T(bf16) ----------
// BK=32 variant of the frozen R7/R9 schedule: LDS 32KB/block -> 4 blocks/CU (was 2),
// doubling latency-hiding TLP. Same 2-deep counted-vmcnt pipeline, raw barriers,
// XOR chunk swizzle (slot = kg ^ ((lr>>1)&3): 2 lanes/bank = free), operand-swapped
// MFMA -> vectorized epilogue. 32 K-tiles, 4 loads/thread/tile, in-loop vmcnt(4).
// EPI: 0 bf16; 2 bf16(v+aux1); 3 bf16(v+aux1+bf16 aux2[idx]); 5 f32;
//      6 bf16(softplus(v+aux1[col])*aux2[col]);
//      7 bf16(silu(v)) stored TRANSPOSED per batch via swizzled-LDS bounce.
template <int EPI, bool BATCHB>
__global__ __launch_bounds__(256, 4)
void k_gemm(const unsigned short* __restrict__ A, const unsigned short* __restrict__ Bt,
            void* __restrict__ outp, const float* __restrict__ aux1,
            const void* __restrict__ aux2) {
  __shared__ unsigned short S[16384];   // 32KB: As dbuf [0,8192), Bs dbuf [8192,16384)
  unsigned short* AsP = S;
  unsigned short* BsP = S + 8192;
  const int tid = threadIdx.x;

  const int nxb = gridDim.x;
  const int nwg = nxb * gridDim.y;
  int lin = blockIdx.y * nxb + blockIdx.x;
  lin = (lin & 7) * (nwg >> 3) + (lin >> 3);
  const int CH = nxb << 3;
  const int grp = lin / CH, idx = lin % CH;
  const int m0 = ((grp << 3) + (idx & 7)) << 7;
  const int n0 = (idx >> 3) << 7;

  const int wid = tid >> 6, l = tid & 63;
  const int wr = ((wid >> 1) << 6);
  const int wc = ((wid & 1) << 6);
  const int lr = l & 15, kg = l >> 4;
  const unsigned short* Bp = BATCHB ? Bt + ((size_t)(m0 >> 10) << 20) : Bt;

  f32x4 acc[4][4];
#pragma unroll
  for (int i = 0; i < 4; ++i)
#pragma unroll
    for (int j = 0; j < 4; ++j) acc[i][j] = (f32x4){0.f, 0.f, 0.f, 0.f};

  // staging: [128 rows][32 cols] per tile; thread -> row tid>>2 (+64 for 2nd load),
  // source chunk pre-swizzled: fchunk = (tid&3) ^ ((row>>1)&3) = (tid&3) ^ ((tid>>3)&3)
  const int frow = tid >> 2;
  const int fchunk = (tid & 3) ^ ((tid >> 3) & 3);
  const unsigned short* ga0 = A  + (size_t)(m0 + frow) * 1024 + (fchunk << 3);
  const unsigned short* ga1 = A  + (size_t)(m0 + frow + 64) * 1024 + (fchunk << 3);
  const unsigned short* gb0 = Bp + (size_t)(n0 + frow) * 1024 + (fchunk << 3);
  const unsigned short* gb1 = Bp + (size_t)(n0 + frow + 64) * 1024 + (fchunk << 3);

#define STAGE(buf)                                                              \
  {                                                                             \
    async_copy16(ga0, AsP + (buf) * 4096 + (tid << 3));                         \
    async_copy16(ga1, AsP + (buf) * 4096 + 2048 + (tid << 3));                  \
    async_copy16(gb0, BsP + (buf) * 4096 + (tid << 3));                         \
    async_copy16(gb1, BsP + (buf) * 4096 + 2048 + (tid << 3));                  \
    ga0 += 32; ga1 += 32; gb0 += 32; gb1 += 32;                                 \
  }

  // read offsets: row r at byte r*64; global chunk kg stored at slot kg^((r>>1)&3);
  // (wr|wc and mi*16 contribute 0 to ((r>>1)&3) -> slot is loop/frag-invariant)
  const int slot = kg ^ ((lr >> 1) & 3);
  const int aOff = ((wr + lr) << 6) + (slot << 4);
  const int bOff = ((wc + lr) << 6) + (slot << 4);
  const char* AsB = (const char*)AsP;
  const char* BsB = (const char*)BsP;

  STAGE(0);
  STAGE(1);   // 8 loads/thread in flight

#pragma unroll
  for (int t = 0; t < 32; ++t) {
    const int cur = t & 1;
    if (t < 31) asm volatile("s_waitcnt vmcnt(4)" ::: "memory");
    else        asm volatile("s_waitcnt vmcnt(0)" ::: "memory");
    __builtin_amdgcn_s_barrier();
    __builtin_amdgcn_sched_barrier(0);
    __builtin_amdgcn_s_setprio(1);
    const char* pa = AsB + (cur << 13);
    const char* pb = BsB + (cur << 13);
    {
      bf16x8 aF[4], bF[4];
#pragma unroll
      for (int mi = 0; mi < 4; ++mi) aF[mi] = *(const bf16x8*)(pa + aOff + mi * 1024);
#pragma unroll
      for (int ni = 0; ni < 4; ++ni) bF[ni] = *(const bf16x8*)(pb + bOff + ni * 1024);
#pragma unroll
      for (int mi = 0; mi < 4; ++mi)
#pragma unroll
        for (int ni = 0; ni < 4; ++ni)
          acc[mi][ni] = __builtin_amdgcn_mfma_f32_16x16x32_bf16(bF[ni], aF[mi], acc[mi][ni], 0, 0, 0);
    }
    __builtin_amdgcn_s_setprio(0);
    asm volatile("s_waitcnt lgkmcnt(0)" ::: "memory");
    __builtin_amdgcn_s_barrier();
    __builtin_amdgcn_sched_barrier(0);
    if (t + 2 < 32) STAGE(cur);
  }
#undef STAGE

  if (EPI == 7) {
    // silu + TRANSPOSED store via swizzled LDS bounce (tile [row t][col d], 256B rows).
    // swizzle: byte ^= ((r&7)^((r>>3)&7))<<4 -> <=2-way conflicts both phases.
    char* ltb = (char*)S;   // full 32KB
#pragma unroll
    for (int mi = 0; mi < 4; ++mi) {
      const int rl = wr + mi * 16 + lr;
      const int sw = (((rl & 7) ^ ((rl >> 3) & 7)) << 4);
#pragma unroll
      for (int ni = 0; ni < 4; ++ni) {
        const int cl = wc + ni * 16 + (kg << 2);
        const f32x4 v = acc[mi][ni];
        ushort4 o;
        o.x = f2b(v[0] / (1.f + __expf(-v[0]))); o.y = f2b(v[1] / (1.f + __expf(-v[1])));
        o.z = f2b(v[2] / (1.f + __expf(-v[2]))); o.w = f2b(v[3] / (1.f + __expf(-v[3])));
        *(ushort4*)(ltb + (((rl << 8) + (cl << 1)) ^ sw)) = o;
      }
    }
    __syncthreads();
    const int bb = m0 >> 10;
    const int tbase = m0 & 1023;
    unsigned short* dstT = (unsigned short*)outp + ((size_t)bb << 20);
#pragma unroll
    for (int it = 0; it < 8; ++it) {
      const int flat = tid + it * 256;
      const int dl = flat >> 4;            // 0..127 (col of tile = d)
      const int tl = (flat & 15) << 3;     // 0..120 (row of tile = t)
      u16x8 o;
#pragma unroll
      for (int j = 0; j < 8; ++j) {
        const int r = tl + j;
        const int sw = (((r & 7) ^ ((r >> 3) & 7)) << 4);
        o[j] = *(const unsigned short*)(ltb + (((r << 8) + (dl << 1)) ^ sw));
      }
      *(u16x8*)&dstT[(size_t)(n0 + dl) * 1024 + tbase + tl] = o;
    }
    return;
  }

  // epilogue (operand-swapped layout): lane l, frag (mi,ni), reg r holds
  // C[m0+wr+mi*16+(l&15)][n0+wc+ni*16+(l>>4)*4+r] -> 4 consecutive cols.
#pragma unroll
  for (int mi = 0; mi < 4; ++mi) {
    const int row = m0 + wr + mi * 16 + lr;
    const size_t rbase = (size_t)row << 10;
#pragma unroll
    for (int ni = 0; ni < 4; ++ni) {
      const int colb = n0 + wc + ni * 16 + (kg << 2);
      const f32x4 v = acc[mi][ni];
      if (EPI == 0) {
        ushort4 o; o.x = f2b(v[0]); o.y = f2b(v[1]); o.z = f2b(v[2]); o.w = f2b(v[3]);
        *(ushort4*)&((unsigned short*)outp)[rbase + colb] = o;
      } else if (EPI == 2) {
        const float4 b4 = *(const float4*)&aux1[colb];
        ushort4 o;
        o.x = f2b(v[0] + b4.x); o.y = f2b(v[1] + b4.y);
        o.z = f2b(v[2] + b4.z); o.w = f2b(v[3] + b4.w);
        *(ushort4*)&((unsigned short*)outp)[rbase + colb] = o;
      } else if (EPI == 3) {
        const float4 b4 = *(const float4*)&aux1[colb];
        const ushort4 xv = *(const ushort4*)&((const unsigned short*)aux2)[rbase + colb];
        ushort4 o;
        o.x = f2b(v[0] + b4.x + b2f(xv.x)); o.y = f2b(v[1] + b4.y + b2f(xv.y));
        o.z = f2b(v[2] + b4.z + b2f(xv.z)); o.w = f2b(v[3] + b4.w + b2f(xv.w));
        *(ushort4*)&((unsigned short*)outp)[rbase + colb] = o;
      } else if (EPI == 5) {
        float4 o; o.x = v[0]; o.y = v[1]; o.z = v[2]; o.w = v[3];
        *(float4*)&((float*)outp)[rbase + colb] = o;
      } else {  // EPI 6: y = softplus(v + bdelta[col]) * A[col], bf16
        const float4 b4 = *(const float4*)&aux1[colb];
        const float4 a4 = *(const float4*)&((const float*)aux2)[colb];
        ushort4 o;
        float t0 = v[0] + b4.x; float sp = (t0 > 15.f) ? t0 : __logf(1.f + __expf(t0));
        o.x = f2b(sp * a4.x);
        float t1 = v[1] + b4.y; sp = (t1 > 15.f) ? t1 : __logf(1.f + __expf(t1));
        o.y = f2b(sp * a4.y);
        float t2 = v[2] + b4.z; sp = (t2 > 15.f) ? t2 : __logf(1.f + __expf(t2));
        o.z = f2b(sp * a4.z);
        float t3 = v[3] + b4.w; sp = (t3 > 15.f) ? t3 : __logf(1.f + __expf(t3));
        o.w = f2b(sp * a4.w);
        *(ushort4*)&((unsigned short*)outp)[rbase + colb] = o;
      }
    }
  }
}

// ---------- launch ----------
extern "C" void kernel_launch(void* const* d_in, const int* in_sizes, int n_in,
                              void* d_out, int out_size, void* d_ws, size_t ws_size,
                              hipStream_t stream) {
  const float* x      = (const float*)d_in[0];
  const float* w1     = (const float*)d_in[1];
  const float* w2     = (const float*)d_in[2];
  const float* w_last = (const float*)d_in[3];
  const float* conv_w = (const float*)d_in[4];
  const float* conv_b = (const float*)d_in[5];
  const float* Avec   = (const float*)d_in[6];
  const float* wB     = (const float*)d_in[7];
  const float* bB     = (const float*)d_in[8];
  const float* wC     = (const float*)d_in[9];
  const float* bC     = (const float*)d_in[10];
  const float* wD     = (const float*)d_in[11];
  const float* bD     = (const float*)d_in[12];
  const float* wdelta = (const float*)d_in[13];
  const float* bdelta = (const float*)d_in[14];

  char* ws = (char*)d_ws;
  const size_t MB = 1ull << 20;
  const size_t NW = 1ull << 20;
  unsigned short* wT   = (unsigned short*)(ws);             // 14MB
  unsigned short* xb   = (unsigned short*)(ws + 14 * MB);   // 16MB; later: ssm
  unsigned short* x1   = (unsigned short*)(ws + 30 * MB);   // 16MB
  unsigned short* xs   = (unsigned short*)(ws + 46 * MB);   // 16MB; later: hb
  unsigned short* y    = (unsigned short*)(ws + 62 * MB);   // 16MB; later: xresT
  unsigned short* z    = (unsigned short*)(ws + 78 * MB);   // 16MB
  unsigned short* Bx   = (unsigned short*)(ws + 94 * MB);   // 16MB
  unsigned short* xD   = (unsigned short*)(ws + 110 * MB);  // 16MB
  float*          cA   = (float*)(ws + 126 * MB);
  float*          cB   = (float*)(ws + 126 * MB + 512 * 1024);
  float*          cwT  = (float*)(ws + 127 * MB);           // 12KB
  unsigned short* hb    = xs;     // reuse (xs consumed before scan23 writes)
  unsigned short* ssm   = xb;     // reuse
  unsigned short* xresT = y;      // reuse (y consumed by scan23 before xres GEMM)

  dim3 bT(32, 8);
  dim3 gG(8, 64);    // nwg=512, now 4 blocks/CU (32KB LDS)

  // prep: weights transpose + conv-w + cast x  (z = 0..15)
  k_prep<<<dim3(32, 32, 16), bT, 0, stream>>>(w1, wdelta, wB, wD, wC, w2, w_last, wT,
                                              conv_w, cwT, x, xb);
  // x1 = xb @ w1
  k_gemm<0, false><<<gG, 256, 0, stream>>>(xb, wT + 0 * NW, x1, nullptr, nullptr);
  // xs = silu(conv(x1))
  k_conv_silu<<<2048, 256, 0, stream>>>(x1, cwT, conv_b, xs);
  // y = softplus(xs@wdelta + bdelta) * A   (bf16)
  k_gemm<6, false><<<gG, 256, 0, stream>>>(xs, wT + 1 * NW, y, bdelta, (const void*)Avec);
  // Bx = xs@wB + bB   (bf16)
  k_gemm<2, false><<<gG, 256, 0, stream>>>(xs, wT + 2 * NW, Bx, bB, nullptr);
  // xD = xs@wD + bD   (bf16)
  k_gemm<2, false><<<gG, 256, 0, stream>>>(xs, wT + 3 * NW, xD, bD, nullptr);
  // scan -> hb  (a_t = exp(-y_t)); scan2 folded into scan23
  k_scan1<<<256, 256, 0, stream>>>(y, Bx, cA, cB);
  k_scan23<<<256, 256, 0, stream>>>(y, Bx, cA, cB, hb);
  // ssm = hb@wC + bC + xD
  k_gemm<3, false><<<gG, 256, 0, stream>>>(hb, wT + 4 * NW, ssm, bC, (const void*)xD);
  // xresT = transpose_b(silu(ssm@w2))  -- transposed store fused into epilogue
  k_gemm<7, false><<<gG, 256, 0, stream>>>(ssm, wT + 5 * NW, xresT, nullptr, nullptr);
  // z = ssm @ x_res (batched via B^T = xresT)
  k_gemm<0, true><<<gG, 256, 0, stream>>>(ssm, xresT, z, nullptr, nullptr);
  // out = z @ w_last (f32)
  k_gemm<5, false><<<gG, 256, 0, stream>>>(z, wT + 6 * NW, (float*)d_out, nullptr, nullptr);
}

// Round 12
// 239.949 us; speedup vs baseline: 1.0542x; 1.0542x over previous
//
#include <hip/hip_runtime.h>

// ---------- types / helpers ----------
typedef __bf16 bf16x8 __attribute__((ext_vector_type(8)));
typedef float  f32x4  __attribute__((ext_vector_type(4)));
typedef unsigned short u16x8 __attribute__((ext_vector_type(8)));

__device__ __forceinline__ float b2f(unsigned short u) {
  union { float f; unsigned int i; } v; v.i = ((unsigned int)u) << 16; return v.f;
}
__device__ __forceinline__ unsigned short f2b(float f) {
  union { float f; unsigned int i; } v; v.f = f;
  unsigned int r = v.i + 0x7fffu + ((v.i >> 16) & 1u);   // RNE
  return (unsigned short)(r >> 16);
}

__device__ __forceinline__ void async_copy16(const unsigned short* g, unsigned short* l) {
  __builtin_amdgcn_global_load_lds(
      (__attribute__((address_space(1))) void*)g,
      (__attribute__((address_space(3))) void*)l, 16, 0, 0);   // offset MUST be 0 (R8 pitfall)
}

// ---------- prep: z<7 weight transpose f32[K][N]->bf16[N][K]; z==7 conv-w; z>=8 cast x ----------
__global__ void k_prep(const float* w0, const float* w1_, const float* w2_,
                       const float* w3_, const float* w4_, const float* w5_,
                       const float* w6_, unsigned short* dst,
                       const float* cw, float* cwT,
                       const float* x, unsigned short* xb) {
  const int tx = threadIdx.x, ty = threadIdx.y;   // 32 x 8
  const int z = blockIdx.z;
  if (z >= 8) {   // cast x [8,1022,1024] f32 -> [8,1024,1024] bf16 (rows 1022/1023 zero)
    const int fb = (z - 8) * 1024 + blockIdx.y * 32 + blockIdx.x;
    const size_t i = ((size_t)(fb * 256 + ty * 32 + tx)) << 2;
    const int d = (int)(i & 1023);
    const int row = (int)(i >> 10);
    const int t = row & 1023, b = row >> 10;
    float4 v = make_float4(0.f, 0.f, 0.f, 0.f);
    if (t < 1022) v = *(const float4*)&x[((size_t)(b * 1022 + t) << 10) + d];
    ushort4 o;
    o.x = f2b(v.x); o.y = f2b(v.y); o.z = f2b(v.z); o.w = f2b(v.w);
    *(ushort4*)&xb[i] = o;
    return;
  }
  if (z == 7) {   // conv weight transpose: cwT[j*1024+d] = cw[d*3+j]
    const int flat = (blockIdx.y * 32 + blockIdx.x) * 256 + ty * 32 + tx;
    if (flat < 3072) {
      const int d = flat & 1023, j = flat >> 10;
      cwT[flat] = cw[d * 3 + j];
    }
    return;
  }
  const float* srcs[7] = {w0, w1_, w2_, w3_, w4_, w5_, w6_};
  const float* src = srcs[z];
  unsigned short* d = dst + ((size_t)z << 20);
  __shared__ float tile[32][33];
  const int bn = blockIdx.x << 5, bk = blockIdx.y << 5;
#pragma unroll
  for (int i = 0; i < 4; ++i)
    tile[ty + i * 8][tx] = src[(size_t)(bk + ty + i * 8) * 1024 + bn + tx];
  __syncthreads();
#pragma unroll
  for (int i = 0; i < 4; ++i)
    d[(size_t)(bn + ty + i * 8) * 1024 + bk + tx] = f2b(tile[tx][ty + i * 8]);
}

// ---------- depthwise conv (k=3) + silu, 4 rows/thread, vectorized x8 ----------
__global__ void k_conv_silu(const unsigned short* __restrict__ x1, const float* __restrict__ cwT,
                            const float* __restrict__ cb, unsigned short* __restrict__ xs) {
  const int gid = blockIdx.x * 256 + threadIdx.x;   // 2048 row-quads * 128 thr
  const int quad = gid >> 7;
  const int d0 = (gid & 127) << 3;
  const int b = quad >> 8, t0 = (quad & 255) << 2;   // rows t0..t0+3
  float w[3][8];
#pragma unroll
  for (int j = 0; j < 3; ++j) {
    float4 a = *(const float4*)&cwT[j * 1024 + d0];
    float4 c = *(const float4*)&cwT[j * 1024 + d0 + 4];
    w[j][0] = a.x; w[j][1] = a.y; w[j][2] = a.z; w[j][3] = a.w;
    w[j][4] = c.x; w[j][5] = c.y; w[j][6] = c.z; w[j][7] = c.w;
  }
  float base[8];
  {
    float4 c0 = *(const float4*)&cb[d0], c1 = *(const float4*)&cb[d0 + 4];
    base[0] = c0.x; base[1] = c0.y; base[2] = c0.z; base[3] = c0.w;
    base[4] = c1.x; base[5] = c1.y; base[6] = c1.z; base[7] = c1.w;
  }
  // rows t0-2 .. t0+3 (6 rows)
  float rv[6][8];
#pragma unroll
  for (int r = 0; r < 6; ++r) {
    const int t = t0 + r - 2;
    if (t >= 0 && t < 1024) {
      u16x8 v = *(const u16x8*)&x1[((size_t)(b * 1024 + t) << 10) + d0];
#pragma unroll
      for (int k = 0; k < 8; ++k) rv[r][k] = b2f(v[k]);
    } else {
#pragma unroll
      for (int k = 0; k < 8; ++k) rv[r][k] = 0.f;
    }
  }
#pragma unroll
  for (int j = 0; j < 4; ++j) {
    u16x8 o;
#pragma unroll
    for (int k = 0; k < 8; ++k) {
      float a = base[k] + rv[j][k] * w[0][k] + rv[j + 1][k] * w[1][k] + rv[j + 2][k] * w[2][k];
      o[k] = f2b(a / (1.f + __expf(-a)));
    }
    *(u16x8*)&xs[((size_t)(b * 1024 + t0 + j) << 10) + d0] = o;
  }
}

// ---------- chunked scan, 2 d-lanes/thread (y=softplus*A bf16; a=exp(-y)) ----------
__global__ void k_scan1(const unsigned short* __restrict__ y, const unsigned short* __restrict__ Bx,
                        float* __restrict__ cA, float* __restrict__ cB) {
  const int p = blockIdx.x * 256 + threadIdx.x;   // 65536
  const int d2 = p & 511, bc = p >> 9;
  const int b = bc >> 4, c = bc & 15;
  const int d0 = d2 << 1;
  size_t base = ((size_t)(b * 1024 + c * 64) << 10) + d0;
  float aA0 = 1.f, aB0 = 0.f, aA1 = 1.f, aB1 = 0.f;
  for (int t = 0; t < 64; ++t) {
    const unsigned int yy = *(const unsigned int*)&y[base];
    const unsigned int bb = *(const unsigned int*)&Bx[base];
    const float a0 = __expf(-b2f((unsigned short)yy));
    const float a1 = __expf(-b2f((unsigned short)(yy >> 16)));
    aA0 *= a0; aB0 = a0 * aB0 + b2f((unsigned short)bb);
    aA1 *= a1; aB1 = a1 * aB1 + b2f((unsigned short)(bb >> 16));
    base += 1024;
  }
  const int gi = (bc << 10) + d0;
  *(float2*)&cA[gi] = make_float2(aA0, aA1);
  *(float2*)&cB[gi] = make_float2(aB0, aB1);
}
// scan2 merged in: each block recomputes its <=15-step prefix from L2-hot cA/cB
__global__ void k_scan23(const unsigned short* __restrict__ y, const unsigned short* __restrict__ Bx,
                         const float* __restrict__ cA, const float* __restrict__ cB,
                         unsigned short* __restrict__ hb) {
  const int p = blockIdx.x * 256 + threadIdx.x;
  const int d2 = p & 511, bc = p >> 9;          // bc uniform per block
  const int b = bc >> 4, c = bc & 15;
  const int d0 = d2 << 1;
  float h0 = 0.f, h1 = 0.f;
  for (int cp = 0; cp < c; ++cp) {              // c uniform per block -> no divergence
    const int gi = (((b << 4) + cp) << 10) + d0;
    const float2 a = *(const float2*)&cA[gi];
    const float2 bb = *(const float2*)&cB[gi];
    h0 = a.x * h0 + bb.x;
    h1 = a.y * h1 + bb.y;
  }
  size_t base = ((size_t)(b * 1024 + c * 64) << 10) + d0;
  for (int t = 0; t < 64; ++t) {
    const unsigned int yy = *(const unsigned int*)&y[base];
    const unsigned int bb = *(const unsigned int*)&Bx[base];
    const float a0 = __expf(-b2f((unsigned short)yy));
    const float a1 = __expf(-b2f((unsigned short)(yy >> 16)));
    h0 = a0 * h0 + b2f((unsigned short)bb);
    h1 = a1 * h1 + b2f((unsigned short)(bb >> 16));
    *(unsigned int*)&hb[base] = (unsigned int)f2b(h0) | ((unsigned int)f2b(h1) << 16);
    base += 1024;
  }
}

// ---------- GEMM: C[8192 x 1024] = A[8192x1024](bf16) * Bt[1024 x 1024]^T(bf16) ----------
// R10 structure verbatim: 128x128 tile, BK=64, 4 waves, 2-deep counted-vmcnt pipeline,
// raw barriers, XOR chunk swizzle, pointer-advance staging, operand-swapped MFMA
// -> vectorized epilogue (row=l&15, 4 consecutive cols per frag).
// EPI: 0 bf16; 2 bf16(v+aux1); 3 bf16(v+aux1+bf16 aux2[idx]); 5 f32;
//      6 bf16(softplus(v+aux1[col])*aux2[col]);
//      7 bf16(silu(v)) stored TRANSPOSED per batch via swizzled-LDS bounce.
template <int EPI, bool BATCHB>
__global__ __launch_bounds__(256)
void k_gemm(const unsigned short* __restrict__ A, const unsigned short* __restrict__ Bt,
            void* __restrict__ outp, const float* __restrict__ aux1,
            const void* __restrict__ aux2) {
  __shared__ unsigned short As[2][128 * 64];   // 32KB; reused as transpose tile in EPI7
  __shared__ unsigned short Bs[2][128 * 64];
  const int tid = threadIdx.x;

  const int nxb = gridDim.x;
  const int nwg = nxb * gridDim.y;
  int lin = blockIdx.y * nxb + blockIdx.x;
  lin = (lin & 7) * (nwg >> 3) + (lin >> 3);
  const int CH = nxb << 3;
  const int grp = lin / CH, idx = lin % CH;
  const int m0 = ((grp << 3) + (idx & 7)) << 7;
  const int n0 = (idx >> 3) << 7;

  const int wid = tid >> 6, l = tid & 63;
  const int wr = ((wid >> 1) << 6);
  const int wc = ((wid & 1) << 6);
  const int lr = l & 15, kg = l >> 4;
  const unsigned short* Bp = BATCHB ? Bt + ((size_t)(m0 >> 10) << 20) : Bt;

  f32x4 acc[4][4];
#pragma unroll
  for (int i = 0; i < 4; ++i)
#pragma unroll
    for (int j = 0; j < 4; ++j) acc[i][j] = (f32x4){0.f, 0.f, 0.f, 0.f};

  const int frow = tid >> 3;
  const int fchunk = (tid & 7) ^ (frow & 7);
  const unsigned short* ga[4];
  const unsigned short* gb[4];
#pragma unroll
  for (int it = 0; it < 4; ++it) {
    ga[it] = A  + (size_t)(m0 + frow + it * 32) * 1024 + (fchunk << 3);
    gb[it] = Bp + (size_t)(n0 + frow + it * 32) * 1024 + (fchunk << 3);
  }

#define STAGE(buf)                                                              \
  {                                                                             \
    _Pragma("unroll")                                                           \
    for (int it = 0; it < 4; ++it)                                              \
      async_copy16(ga[it], &As[buf][(tid << 3) + it * 2048]);                   \
    _Pragma("unroll")                                                           \
    for (int it = 0; it < 4; ++it)                                              \
      async_copy16(gb[it], &Bs[buf][(tid << 3) + it * 2048]);                   \
    _Pragma("unroll")                                                           \
    for (int it = 0; it < 4; ++it) { ga[it] += 64; gb[it] += 64; }              \
  }

  const int c0 = kg ^ (lr & 7);
  const int aOff0 = ((wr + lr) << 7) + (c0 << 4);
  const int aOff1 = aOff0 ^ 64;
  const int bOff0 = ((wc + lr) << 7) + (c0 << 4);
  const int bOff1 = bOff0 ^ 64;
  const char* AsB = (const char*)&As[0][0];
  const char* BsB = (const char*)&Bs[0][0];

  STAGE(0);
  STAGE(1);

#pragma unroll
  for (int t = 0; t < 16; ++t) {
    const int cur = t & 1;
    if (t < 15) asm volatile("s_waitcnt vmcnt(8)" ::: "memory");
    else        asm volatile("s_waitcnt vmcnt(0)" ::: "memory");
    __builtin_amdgcn_s_barrier();
    __builtin_amdgcn_sched_barrier(0);
    __builtin_amdgcn_s_setprio(1);
    const char* pa = AsB + (cur << 14);
    const char* pb = BsB + (cur << 14);
    {
      bf16x8 aF[4], bF[4];
#pragma unroll
      for (int mi = 0; mi < 4; ++mi) aF[mi] = *(const bf16x8*)(pa + aOff0 + mi * 2048);
#pragma unroll
      for (int ni = 0; ni < 4; ++ni) bF[ni] = *(const bf16x8*)(pb + bOff0 + ni * 2048);
#pragma unroll
      for (int mi = 0; mi < 4; ++mi)
#pragma unroll
        for (int ni = 0; ni < 4; ++ni)
          acc[mi][ni] = __builtin_amdgcn_mfma_f32_16x16x32_bf16(bF[ni], aF[mi], acc[mi][ni], 0, 0, 0);
    }
    {
      bf16x8 aF[4], bF[4];
#pragma unroll
      for (int mi = 0; mi < 4; ++mi) aF[mi] = *(const bf16x8*)(pa + aOff1 + mi * 2048);
#pragma unroll
      for (int ni = 0; ni < 4; ++ni) bF[ni] = *(const bf16x8*)(pb + bOff1 + ni * 2048);
#pragma unroll
      for (int mi = 0; mi < 4; ++mi)
#pragma unroll
        for (int ni = 0; ni < 4; ++ni)
          acc[mi][ni] = __builtin_amdgcn_mfma_f32_16x16x32_bf16(bF[ni], aF[mi], acc[mi][ni], 0, 0, 0);
    }
    __builtin_amdgcn_s_setprio(0);
    asm volatile("s_waitcnt lgkmcnt(0)" ::: "memory");
    __builtin_amdgcn_s_barrier();
    __builtin_amdgcn_sched_barrier(0);
    if (t + 2 < 16) STAGE(cur);
  }
#undef STAGE

  if (EPI == 7) {
    // silu + TRANSPOSED store via swizzled LDS bounce (tile [row t][col d], 256B rows).
    // swizzle: byte ^= ((r&7)^((r>>3)&7))<<4 -> <=2-way conflicts both phases.
    char* ltb = (char*)&As[0][0];   // 32KB
#pragma unroll
    for (int mi = 0; mi < 4; ++mi) {
      const int rl = wr + mi * 16 + lr;
      const int sw = (((rl & 7) ^ ((rl >> 3) & 7)) << 4);
#pragma unroll
      for (int ni = 0; ni < 4; ++ni) {
        const int cl = wc + ni * 16 + (kg << 2);
        const f32x4 v = acc[mi][ni];
        ushort4 o;
        o.x = f2b(v[0] / (1.f + __expf(-v[0]))); o.y = f2b(v[1] / (1.f + __expf(-v[1])));
        o.z = f2b(v[2] / (1.f + __expf(-v[2]))); o.w = f2b(v[3] / (1.f + __expf(-v[3])));
        *(ushort4*)(ltb + (((rl << 8) + (cl << 1)) ^ sw)) = o;
      }
    }
    __syncthreads();
    const int bb = m0 >> 10;
    const int tbase = m0 & 1023;
    unsigned short* dstT = (unsigned short*)outp + ((size_t)bb << 20);
#pragma unroll
    for (int it = 0; it < 8; ++it) {
      const int flat = tid + it * 256;
      const int dl = flat >> 4;            // 0..127 (col of tile = d)
      const int tl = (flat & 15) << 3;     // 0..120 (row of tile = t)
      u16x8 o;
#pragma unroll
      for (int j = 0; j < 8; ++j) {
        const int r = tl + j;
        const int sw = (((r & 7) ^ ((r >> 3) & 7)) << 4);
        o[j] = *(const unsigned short*)(ltb + (((r << 8) + (dl << 1)) ^ sw));
      }
      *(u16x8*)&dstT[(size_t)(n0 + dl) * 1024 + tbase + tl] = o;
    }
    return;
  }

  // epilogue (operand-swapped layout): lane l, frag (mi,ni), reg r holds
  // C[m0+wr+mi*16+(l&15)][n0+wc+ni*16+(l>>4)*4+r] -> 4 consecutive cols.
#pragma unroll
  for (int mi = 0; mi < 4; ++mi) {
    const int row = m0 + wr + mi * 16 + lr;
    const size_t rbase = (size_t)row << 10;
#pragma unroll
    for (int ni = 0; ni < 4; ++ni) {
      const int colb = n0 + wc + ni * 16 + (kg << 2);
      const f32x4 v = acc[mi][ni];
      if (EPI == 0) {
        ushort4 o; o.x = f2b(v[0]); o.y = f2b(v[1]); o.z = f2b(v[2]); o.w = f2b(v[3]);
        *(ushort4*)&((unsigned short*)outp)[rbase + colb] = o;
      } else if (EPI == 2) {
        const float4 b4 = *(const float4*)&aux1[colb];
        ushort4 o;
        o.x = f2b(v[0] + b4.x); o.y = f2b(v[1] + b4.y);
        o.z = f2b(v[2] + b4.z); o.w = f2b(v[3] + b4.w);
        *(ushort4*)&((unsigned short*)outp)[rbase + colb] = o;
      } else if (EPI == 3) {
        const float4 b4 = *(const float4*)&aux1[colb];
        const ushort4 xv = *(const ushort4*)&((const unsigned short*)aux2)[rbase + colb];
        ushort4 o;
        o.x = f2b(v[0] + b4.x + b2f(xv.x)); o.y = f2b(v[1] + b4.y + b2f(xv.y));
        o.z = f2b(v[2] + b4.z + b2f(xv.z)); o.w = f2b(v[3] + b4.w + b2f(xv.w));
        *(ushort4*)&((unsigned short*)outp)[rbase + colb] = o;
      } else if (EPI == 5) {
        float4 o; o.x = v[0]; o.y = v[1]; o.z = v[2]; o.w = v[3];
        *(float4*)&((float*)outp)[rbase + colb] = o;
      } else {  // EPI 6: y = softplus(v + bdelta[col]) * A[col], bf16
        const float4 b4 = *(const float4*)&aux1[colb];
        const float4 a4 = *(const float4*)&((const float*)aux2)[colb];
        ushort4 o;
        float t0 = v[0] + b4.x; float sp = (t0 > 15.f) ? t0 : __logf(1.f + __expf(t0));
        o.x = f2b(sp * a4.x);
        float t1 = v[1] + b4.y; sp = (t1 > 15.f) ? t1 : __logf(1.f + __expf(t1));
        o.y = f2b(sp * a4.y);
        float t2 = v[2] + b4.z; sp = (t2 > 15.f) ? t2 : __logf(1.f + __expf(t2));
        o.z = f2b(sp * a4.z);
        float t3 = v[3] + b4.w; sp = (t3 > 15.f) ? t3 : __logf(1.f + __expf(t3));
        o.w = f2b(sp * a4.w);
        *(ushort4*)&((unsigned short*)outp)[rbase + colb] = o;
      }
    }
  }
}

// ---------- launch ----------
extern "C" void kernel_launch(void* const* d_in, const int* in_sizes, int n_in,
                              void* d_out, int out_size, void* d_ws, size_t ws_size,
                              hipStream_t stream) {
  const float* x      = (const float*)d_in[0];
  const float* w1     = (const float*)d_in[1];
  const float* w2     = (const float*)d_in[2];
  const float* w_last = (const float*)d_in[3];
  const float* conv_w = (const float*)d_in[4];
  const float* conv_b = (const float*)d_in[5];
  const float* Avec   = (const float*)d_in[6];
  const float* wB     = (const float*)d_in[7];
  const float* bB     = (const float*)d_in[8];
  const float* wC     = (const float*)d_in[9];
  const float* bC     = (const float*)d_in[10];
  const float* wD     = (const float*)d_in[11];
  const float* bD     = (const float*)d_in[12];
  const float* wdelta = (const float*)d_in[13];
  const float* bdelta = (const float*)d_in[14];

  char* ws = (char*)d_ws;
  const size_t MB = 1ull << 20;
  const size_t NW = 1ull << 20;
  unsigned short* wT   = (unsigned short*)(ws);             // 14MB
  unsigned short* xb   = (unsigned short*)(ws + 14 * MB);   // 16MB; later: ssm
  unsigned short* x1   = (unsigned short*)(ws + 30 * MB);   // 16MB
  unsigned short* xs   = (unsigned short*)(ws + 46 * MB);   // 16MB; later: hb
  unsigned short* y    = (unsigned short*)(ws + 62 * MB);   // 16MB; later: xresT
  unsigned short* z    = (unsigned short*)(ws + 78 * MB);   // 16MB
  unsigned short* Bx   = (unsigned short*)(ws + 94 * MB);   // 16MB
  unsigned short* xD   = (unsigned short*)(ws + 110 * MB);  // 16MB
  float*          cA   = (float*)(ws + 126 * MB);
  float*          cB   = (float*)(ws + 126 * MB + 512 * 1024);
  float*          cwT  = (float*)(ws + 127 * MB);           // 12KB
  unsigned short* hb    = xs;     // reuse (xs consumed before scan23 writes)
  unsigned short* ssm   = xb;     // reuse
  unsigned short* xresT = y;      // reuse (y consumed by scan23 before xres GEMM)

  dim3 bT(32, 8);
  dim3 gG(8, 64);    // nwg=512, 2 blocks/CU

  // prep: weights transpose + conv-w + cast x  (z = 0..15)
  k_prep<<<dim3(32, 32, 16), bT, 0, stream>>>(w1, wdelta, wB, wD, wC, w2, w_last, wT,
                                              conv_w, cwT, x, xb);
  // x1 = xb @ w1
  k_gemm<0, false><<<gG, 256, 0, stream>>>(xb, wT + 0 * NW, x1, nullptr, nullptr);
  // xs = silu(conv(x1))
  k_conv_silu<<<1024, 256, 0, stream>>>(x1, cwT, conv_b, xs);
  // y = softplus(xs@wdelta + bdelta) * A   (bf16)
  k_gemm<6, false><<<gG, 256, 0, stream>>>(xs, wT + 1 * NW, y, bdelta, (const void*)Avec);
  // Bx = xs@wB + bB   (bf16)
  k_gemm<2, false><<<gG, 256, 0, stream>>>(xs, wT + 2 * NW, Bx, bB, nullptr);
  // xD = xs@wD + bD   (bf16)
  k_gemm<2, false><<<gG, 256, 0, stream>>>(xs, wT + 3 * NW, xD, bD, nullptr);
  // scan -> hb  (a_t = exp(-y_t)); scan2 folded into scan23
  k_scan1<<<256, 256, 0, stream>>>(y, Bx, cA, cB);
  k_scan23<<<256, 256, 0, stream>>>(y, Bx, cA, cB, hb);
  // ssm = hb@wC + bC + xD
  k_gemm<3, false><<<gG, 256, 0, stream>>>(hb, wT + 4 * NW, ssm, bC, (const void*)xD);
  // xresT = transpose_b(silu(ssm@w2))  -- transposed store fused into epilogue
  k_gemm<7, false><<<gG, 256, 0, stream>>>(ssm, wT + 5 * NW, xresT, nullptr, nullptr);
  // z = ssm @ x_res (batched via B^T = xresT)
  k_gemm<0, true><<<gG, 256, 0, stream>>>(ssm, xresT, z, nullptr, nullptr);
  // out = z @ w_last (f32)
  k_gemm<5, false><<<gG, 256, 0, stream>>>(z, wT + 6 * NW, (float*)d_out, nullptr, nullptr);
}